// Round 17
// baseline (172.921 us; speedup 1.0000x reference)
//
#include <hip/hip_runtime.h>
#include <hip/hip_bf16.h>

// Problem constants (B=8192, D=128 from reference setup_inputs)
constexpr int Bh = 8192;
constexpr int Nn = 16384;   // 2*B
constexpr int Dd = 128;
constexpr float EPS = 1e-8f;
constexpr float LN2 = 0.69314718056f;

// Geometry: 128-row x 64-col half-tiles, 16 KB staged B, 32 KB LDS dbuf.
// 512-thread blocks, 8 waves = 4 row-groups (32r) x 2 col-groups (32c).
// cum2(t) = t*(257-t); total 128*129 = 16512.
constexpr int K_TILES = 8;          // half-tiles per block
constexpr int N_TILES = 16512;
constexpr int N_BLOCKS = N_TILES / K_TILES;   // 2064, exact

typedef short bf16x8 __attribute__((ext_vector_type(8)));
typedef float f32x4 __attribute__((ext_vector_type(4)));

// ---- Kernel 1: fp32 -> bf16 z buffer (4 MB, per-XCD-L2-resident: R11 proved
// this buffer is load-bearing). Also zeroes rowsum, ticket counter, possum.
__global__ __launch_bounds__(256) void convert_kernel(const float4* __restrict__ za,
                                                      const float4* __restrict__ zb,
                                                      ushort* __restrict__ z,
                                                      float* __restrict__ rowsum,
                                                      int* __restrict__ counter,
                                                      float* __restrict__ possum) {
    const int t = blockIdx.x * 256 + threadIdx.x;        // 0 .. 524287
    constexpr int Q = (Bh * Dd) / 4;                     // 262144 float4 per input
    const float SCL = 1.69864363f;                       // sqrt(2 * 1.4426950409)
    float4 v = (t < Q) ? za[t] : zb[t - Q];
    union { ushort4 u4; __hip_bfloat16 h[4]; } cv;
    cv.h[0] = __float2bfloat16(v.x * SCL);
    cv.h[1] = __float2bfloat16(v.y * SCL);
    cv.h[2] = __float2bfloat16(v.z * SCL);
    cv.h[3] = __float2bfloat16(v.w * SCL);
    ((ushort4*)z)[t] = cv.u4;
    if (t < Nn) rowsum[t] = 0.f;
    if (t == 0) { counter[0] = 0; possum[0] = 0.f; }
}

// half-tile index g -> row tile t: largest t with cum2(t) = t*(257-t) <= g
__device__ __forceinline__ int row_tile_of(int g) {
    int t = (int)((257.0f - sqrtf((float)(66049 - 4 * g))) * 0.5f);
    t = t < 0 ? 0 : (t > 127 ? 127 : t);
    while (t * (257 - t) > g) --t;
    while ((t + 1) * (256 - t) <= g) ++t;
    return t;
}

// row-credit flush: reduce rs over the 16 col-lanes, one atomic per row.
// (Both col-group waves of a row-group flush the same rows: atomic, fine.)
__device__ __forceinline__ void flush_rs(float* __restrict__ rowsum, int rowW,
                                         float (&rs)[2][4], int q, int c) {
#pragma unroll
    for (int s = 0; s < 2; ++s)
#pragma unroll
        for (int r = 0; r < 4; ++r) {
            float v = rs[s][r];
            v += __shfl_xor(v, 1);
            v += __shfl_xor(v, 2);
            v += __shfl_xor(v, 4);
            v += __shfl_xor(v, 8);
            if (c == 0) atomicAdd(&rowsum[rowW + s * 16 + q * 4 + r], v);
            rs[s][r] = 0.f;
        }
}

// col-credit flush (deferred one half-tile): reduce over q, one atomic per col.
// Each wave covers its own 32-col group (base = C0P + cg*32).
__device__ __forceinline__ void colflush(float* __restrict__ rowsum,
                                         float (&csumP)[2], int base, int lane, int c) {
#pragma unroll
    for (int st = 0; st < 2; ++st) {
        float v = csumP[st];
        v += __shfl_xor(v, 16);
        v += __shfl_xor(v, 32);
        if (lane < 16) atomicAdd(&rowsum[base + st * 16 + c], v);
    }
}

// Stage one 64-col x 128-K bf16 B half-tile (16 KB) into LDS via
// global_load_lds width-16, XOR-swizzled via the GLOBAL source address (m173).
// 8 waves x 2 chunks of 1 KB = 16 KB.
__device__ __forceinline__ void stage_tile(const ushort* __restrict__ z, ushort* lbuf,
                                           int C0, int wave, int lane) {
#pragma unroll
    for (int i = 0; i < 2; ++i) {
        const int chunk = wave * 2 + i;              // 16 chunks of 1 KB
        const int r = (chunk << 2) + (lane >> 4);    // col 0..63 of this half-tile
        const int bl = ((lane & 15) ^ (r & 15)) << 4;  // swizzled byte-in-row
        const char* gp = (const char*)z + (((size_t)(C0 + r)) << 8) + bl;
        ushort* lp = lbuf + (chunk << 9);            // wave-uniform LDS base
        __builtin_amdgcn_global_load_lds((const __attribute__((address_space(1))) void*)gp,
                                         (__attribute__((address_space(3))) void*)lp,
                                         16, 0, 0);
    }
}

// ---- Kernel 2: 512 threads / 8 waves; wave = 32 rows (2 subtiles) x 32 cols
// (2 sts of its col-group). R16 BUG FIX: R16 gave each wave a single 16-row
// A-frag at 32-row stride -> half the rows never computed (absmax 3.81).
// Restored afrag[2][4] + s-loop (R10's row coverage) at the 8-wave split.
// MFMA/block/tile = 8 waves x 2st x 2s x 4kt = 128 = (128x64xK128) exact.
// Per-output LDS traffic unchanged vs R10 (64 KB read per 16 KB tile).
__global__ __launch_bounds__(512) void main_kernel(const ushort* __restrict__ z,
                                                   float* __restrict__ rowsum,
                                                   int* __restrict__ counter,
                                                   float* __restrict__ possum,
                                                   float* __restrict__ out) {
    __shared__ ushort ldsb[2][8192];      // 2 x 16 KB B half-tile double buffer

    const int tid = threadIdx.x;
    const int wave = tid >> 6;      // 0..7
    const int wr = wave >> 1;       // row group 0..3 (32 rows each)
    const int cg = wave & 1;        // col group 0..1 (32 cols each)
    const int lane = tid & 63;
    const int q = lane >> 4;        // quad: 0..3
    const int c = lane & 15;        // 0..15
    const int g0 = blockIdx.x * K_TILES;

    int tr = row_tile_of(g0);
    int ct = 2 * tr + (g0 - tr * (257 - tr));   // col half-tile 0..255

    // per-lane swizzled LDS fragment offsets: logical 16B-unit (q+4kt) in row c
    int O[4];
#pragma unroll
    for (int kt = 0; kt < 4; ++kt) O[kt] = (c << 8) + ((((q + 4 * kt) ^ c)) << 4);

    bf16x8 afrag[2][4];
    float rs[2][4];
#pragma unroll
    for (int s = 0; s < 2; ++s)
#pragma unroll
        for (int r = 0; r < 4; ++r) rs[s][r] = 0.f;

    const f32x4 Z4 = {0.f, 0.f, 0.f, 0.f};

    float pacc = 0.f;               // this lane's positive-pair log contributions
    float csumP[2];
    int baseP = 0;
    bool pendP = false;
    int cur_tr = -1, rowW = 0, cur = 0;

    stage_tile(z, &ldsb[0][0], ct << 6, wave, lane);
    __syncthreads();

    for (int j = 0; j < K_TILES; ++j) {
        const int C0 = ct << 6;                 // column base (64-wide)
        const bool diag = ((ct >> 1) == tr);    // inside the diagonal 128x128

        if (tr != cur_tr) {                 // row-panel change: flush + reload A
            if (cur_tr >= 0) flush_rs(rowsum, rowW, rs, q, c);
            cur_tr = tr;
            rowW = (tr << 7) + wr * 32;     // this wave's 32-row base
#pragma unroll
            for (int s = 0; s < 2; ++s) {
                const ushort* ap = z + (size_t)(rowW + s * 16 + c) * Dd;
#pragma unroll
                for (int kt = 0; kt < 4; ++kt)
                    afrag[s][kt] = *(const bf16x8*)(ap + kt * 32 + q * 8);
            }
        }

        // deferred col-credit flush from previous half-tile
        if (pendP) { colflush(rowsum, csumP, baseP, lane, c); pendP = false; }

        // next half-tile coords + prefetch-stage into the other buffer
        int trN = tr, ctN = ct + 1;
        if (ctN == 256) { trN = tr + 1; ctN = 2 * trN; }
        if (j + 1 < K_TILES) stage_tile(z, &ldsb[cur ^ 1][0], ctN << 6, wave, lane);

        const char* lb = (const char*)&ldsb[cur][0];
        float csum[2] = {0.f, 0.f};

        // ---- acc-pipelined phase loop: 3 phases over this wave's 2 sts.
        f32x4 acc[2][2];
#pragma unroll
        for (int st = 0; st < 3; ++st) {
            const int p = st & 1;
            if (st < 2) {
                const int stG = cg * 2 + st;    // global st 0..3
                bf16x8 bcur[4];
#pragma unroll
                for (int kt = 0; kt < 4; ++kt)
                    bcur[kt] = *(const bf16x8*)(lb + O[kt] + stG * 4096);
#pragma unroll
                for (int s = 0; s < 2; ++s)
                    acc[p][s] = __builtin_amdgcn_mfma_f32_16x16x32_bf16(afrag[s][0], bcur[0], Z4, 0, 0, 0);
#pragma unroll
                for (int kt = 1; kt < 4; ++kt) {
#pragma unroll
                    for (int s = 0; s < 2; ++s)
                        acc[p][s] = __builtin_amdgcn_mfma_f32_16x16x32_bf16(afrag[s][kt], bcur[kt], acc[p][s], 0, 0, 0);
                }
            }
            if (st > 0) {
                const int stP = st - 1;         // phase being finished
                const int pp = p ^ 1;
                const int gc0 = C0 + (cg * 2 + stP) * 16;
#pragma unroll
                for (int s = 0; s < 2; ++s) {
                    const int R = rowW + s * 16;
                    float sp[4];
#pragma unroll
                    for (int r = 0; r < 4; ++r) {
                        float u = acc[pp][s][r];
                        // softplus scaled by log2e: max(u,0) + log2(1 + 2^-|u|)
                        float e = __builtin_amdgcn_exp2f(-fabsf(u));
                        sp[r] = fmaxf(u, 0.f) + __builtin_amdgcn_logf(1.f + e);
                    }
                    if (diag && gc0 == R) {               // zero self-similarity
#pragma unroll
                        for (int r = 0; r < 4; ++r)
                            if (c == q * 4 + r) sp[r] = 0.f;
                    }
                    if (gc0 == (R ^ Bh)) {                // positive-pair subtile
                        // (wave-uniform; rare; R<Bh guaranteed: R>=Bh would
                        // be below-diagonal and never enumerated here)
#pragma unroll
                        for (int r = 0; r < 4; ++r)
                            if (c == q * 4 + r)
                                pacc += __logf(fmaxf(LN2 * sp[r], EPS));
                    }
#pragma unroll
                    for (int r = 0; r < 4; ++r) rs[s][r] += sp[r];
                    if (!diag) csum[stP] += (sp[0] + sp[1]) + (sp[2] + sp[3]);
                }
            }
        }

        if (!diag) {    // defer the col-credit atomics past the barrier
            csumP[0] = csum[0];
            csumP[1] = csum[1];
            baseP = C0 + cg * 32;
            pendP = true;
        }

        __syncthreads();        // drains vmcnt(0): stage + atomics all a phase old
        cur ^= 1;
        tr = trN;
        ct = ctN;
    }

    if (pendP) colflush(rowsum, csumP, baseP, lane, c);
    if (cur_tr >= 0) flush_rs(rowsum, rowW, rs, q, c);

    // positive-pair contribution: wave-reduce pacc, one atomic per wave (x2:
    // each pair element appears twice in the full N-sum)
    {
        float v = pacc;
#pragma unroll
        for (int m = 1; m < 64; m <<= 1) v += __shfl_xor(v, m);
        if (lane == 0 && v != 0.f) atomicAdd(possum, v + v);
    }

    // ---- last-block finalize (no fences; ILP-batched loads) ----
    __syncthreads();                       // barrier drain: all my atomics done
    int* shi = (int*)&ldsb[0][0];          // LDS dead now: reuse
    if (tid == 0) shi[0] = atomicAdd(counter, 1);
    __syncthreads();
    if (shi[0] == N_BLOCKS - 1) {
        float acc = 0.f;                   // sum of log(denom_i)
        // 16384 / 512 threads = 32 elems/thread; 4 batches of 8 independent
        // loads -> ~4 coherent-point round-trips instead of 32.
#pragma unroll
        for (int b = 0; b < 4; ++b) {
            float v[8];
#pragma unroll
            for (int k = 0; k < 8; ++k)
                v[k] = __hip_atomic_load(&rowsum[tid + (b * 8 + k) * 512],
                                         __ATOMIC_RELAXED, __HIP_MEMORY_SCOPE_AGENT);
#pragma unroll
            for (int k = 0; k < 8; ++k)
                acc += __logf(fmaxf(LN2 * v[k], EPS));
        }
#pragma unroll
        for (int m = 1; m < 64; m <<= 1) acc += __shfl_xor(acc, m);
        __syncthreads();                   // all have read shi[0]
        float* red = (float*)&ldsb[0][0];
        if (lane == 0) red[wave] = acc;
        __syncthreads();
        if (tid == 0) {
            float ps = __hip_atomic_load(possum, __ATOMIC_RELAXED, __HIP_MEMORY_SCOPE_AGENT);
            float sumden = red[0] + red[1] + red[2] + red[3]
                         + red[4] + red[5] + red[6] + red[7];
            out[0] = (sumden - ps) / (float)Nn;   // = -(possum - sum(log denom))/N
        }
    }
}

extern "C" void kernel_launch(void* const* d_in, const int* in_sizes, int n_in,
                              void* d_out, int out_size, void* d_ws, size_t ws_size,
                              hipStream_t stream) {
    const float* za = (const float*)d_in[0];
    const float* zb = (const float*)d_in[1];

    // workspace layout: z bf16 (4 MB) | rowsum (16384 f) | counter | possum
    ushort* z = (ushort*)d_ws;
    float* rowsum = (float*)((char*)d_ws + (size_t)Nn * Dd * 2);
    int* counter = (int*)(rowsum + Nn);
    float* possum = (float*)(rowsum + Nn + 32);
    float* out = (float*)d_out;

    convert_kernel<<<2048, 256, 0, stream>>>((const float4*)za, (const float4*)zb, z, rowsum, counter, possum);
    main_kernel<<<N_BLOCKS, 512, 0, stream>>>(z, rowsum, counter, possum, out);
}

// Round 18
// 169.691 us; speedup vs baseline: 1.0190x; 1.0190x over previous
//
#include <hip/hip_runtime.h>
#include <hip/hip_bf16.h>

// Problem constants (B=8192, D=128 from reference setup_inputs)
constexpr int Bh = 8192;
constexpr int Nn = 16384;   // 2*B
constexpr int Dd = 128;
constexpr float EPS = 1e-8f;
constexpr float LN2 = 0.69314718056f;

// Geometry (R15, best-measured structure): 128-row x 64-col half-tiles,
// 16 KB staged B, 32 KB LDS dbuf, 256 thr / 4 waves.
// cum2(t) = t*(257-t); total 128*129 = 16512.
constexpr int K_TILES = 16;         // half-tiles per block
constexpr int N_TILES = 16512;
constexpr int N_BLOCKS = N_TILES / K_TILES;   // 1032, exact

typedef short bf16x8 __attribute__((ext_vector_type(8)));
typedef float f32x4 __attribute__((ext_vector_type(4)));

// ---- Kernel 1: fp32 -> bf16 z buffer (4 MB, per-XCD-L2-resident: R11 proved
// this buffer is load-bearing). Also zeroes rowsum, ticket counter, possum.
__global__ __launch_bounds__(256) void convert_kernel(const float4* __restrict__ za,
                                                      const float4* __restrict__ zb,
                                                      ushort* __restrict__ z,
                                                      float* __restrict__ rowsum,
                                                      int* __restrict__ counter,
                                                      float* __restrict__ possum) {
    const int t = blockIdx.x * 256 + threadIdx.x;        // 0 .. 524287
    constexpr int Q = (Bh * Dd) / 4;                     // 262144 float4 per input
    const float SCL = 1.69864363f;                       // sqrt(2 * 1.4426950409)
    float4 v = (t < Q) ? za[t] : zb[t - Q];
    union { ushort4 u4; __hip_bfloat16 h[4]; } cv;
    cv.h[0] = __float2bfloat16(v.x * SCL);
    cv.h[1] = __float2bfloat16(v.y * SCL);
    cv.h[2] = __float2bfloat16(v.z * SCL);
    cv.h[3] = __float2bfloat16(v.w * SCL);
    ((ushort4*)z)[t] = cv.u4;
    if (t < Nn) rowsum[t] = 0.f;
    if (t == 0) { counter[0] = 0; possum[0] = 0.f; }
}

// half-tile index g -> row tile t: largest t with cum2(t) = t*(257-t) <= g
__device__ __forceinline__ int row_tile_of(int g) {
    int t = (int)((257.0f - sqrtf((float)(66049 - 4 * g))) * 0.5f);
    t = t < 0 ? 0 : (t > 127 ? 127 : t);
    while (t * (257 - t) > g) --t;
    while ((t + 1) * (256 - t) <= g) ++t;
    return t;
}

// row-credit flush: reduce rs over the 16 col-lanes, one atomic per row
__device__ __forceinline__ void flush_rs(float* __restrict__ rowsum, int rowW,
                                         float (&rs)[2][4], int q, int c) {
#pragma unroll
    for (int s = 0; s < 2; ++s)
#pragma unroll
        for (int r = 0; r < 4; ++r) {
            float v = rs[s][r];
            v += __shfl_xor(v, 1);
            v += __shfl_xor(v, 2);
            v += __shfl_xor(v, 4);
            v += __shfl_xor(v, 8);
            if (c == 0) atomicAdd(&rowsum[rowW + s * 16 + q * 4 + r], v);
            rs[s][r] = 0.f;
        }
}

// col-credit flush (deferred one half-tile): reduce over q, one atomic per col
__device__ __forceinline__ void colflush(float* __restrict__ rowsum,
                                         float (&csumP)[4], int C0P, int lane, int c) {
#pragma unroll
    for (int st = 0; st < 4; ++st) {
        float v = csumP[st];
        v += __shfl_xor(v, 16);
        v += __shfl_xor(v, 32);
        if (lane < 16) atomicAdd(&rowsum[C0P + st * 16 + c], v);
    }
}

// Stage one 64-col x 128-K bf16 B half-tile (16 KB) into LDS via
// global_load_lds width-16, XOR-swizzled via the GLOBAL source address (m173).
__device__ __forceinline__ void stage_tile(const ushort* __restrict__ z, ushort* lbuf,
                                           int C0, int wave, int lane) {
#pragma unroll
    for (int i = 0; i < 4; ++i) {
        const int chunk = wave * 4 + i;              // 16 chunks of 1 KB
        const int r = (chunk << 2) + (lane >> 4);    // col 0..63 of this half-tile
        const int bl = ((lane & 15) ^ (r & 15)) << 4;  // swizzled byte-in-row
        const char* gp = (const char*)z + (((size_t)(C0 + r)) << 8) + bl;
        ushort* lp = lbuf + (chunk << 9);            // wave-uniform LDS base
        __builtin_amdgcn_global_load_lds((const __attribute__((address_space(1))) void*)gp,
                                         (__attribute__((address_space(3))) void*)lp,
                                         16, 0, 0);
    }
}

// ---- Kernel 2: R15 structure, softplus log2 replaced by a degree-5 minimax
// polynomial. R9 priced the two trans ops at 48 us of main's 125 (7x the
// static model); R17 closed the TLP axis (VALUBusy pinned ~52% at 16/21/36%
// occupancy). This swap removes HALF the trans ops with ZERO structural
// change (same accumulators, same ILP, same control flow — R7's confounds
// absent). Poly: log2(1+e), e in (0,1], A&S 4.1.33 x log2e, |err|<=1.5e-4
// (loss threshold 0.34; bf16 sim quantization dominates). Exact-log paths
// kept where cheap: pacc (rare) and finalize (16k elems).
__global__ __launch_bounds__(256) void main_kernel(const ushort* __restrict__ z,
                                                   float* __restrict__ rowsum,
                                                   int* __restrict__ counter,
                                                   float* __restrict__ possum,
                                                   float* __restrict__ out) {
    __shared__ ushort ldsb[2][8192];      // 2 x 16 KB B half-tile double buffer

    const int tid = threadIdx.x;
    const int wave = tid >> 6;
    const int lane = tid & 63;
    const int q = lane >> 4;        // quad: 0..3
    const int c = lane & 15;        // 0..15
    const int g0 = blockIdx.x * K_TILES;

    int tr = row_tile_of(g0);
    int ct = 2 * tr + (g0 - tr * (257 - tr));   // col half-tile 0..255

    // per-lane swizzled LDS fragment offsets: logical 16B-unit (q+4kt) in row c
    int O[4];
#pragma unroll
    for (int kt = 0; kt < 4; ++kt) O[kt] = (c << 8) + ((((q + 4 * kt) ^ c)) << 4);

    bf16x8 afrag[2][4];
    float rs[2][4];
#pragma unroll
    for (int s = 0; s < 2; ++s)
#pragma unroll
        for (int r = 0; r < 4; ++r) rs[s][r] = 0.f;

    const f32x4 Z4 = {0.f, 0.f, 0.f, 0.f};

    float pacc = 0.f;               // this lane's positive-pair log contributions
    float csumP[4];
    int C0P = 0;
    bool pendP = false;
    int cur_tr = -1, rowW = 0, cur = 0;

    stage_tile(z, &ldsb[0][0], ct << 6, wave, lane);
    __syncthreads();

    for (int j = 0; j < K_TILES; ++j) {
        const int C0 = ct << 6;                 // column base (64-wide)
        const bool diag = ((ct >> 1) == tr);    // inside the diagonal 128x128

        if (tr != cur_tr) {                 // row-panel change: flush + reload A
            if (cur_tr >= 0) flush_rs(rowsum, rowW, rs, q, c);
            cur_tr = tr;
            rowW = (tr << 7) + wave * 32;   // this wave's 32-row base
#pragma unroll
            for (int s = 0; s < 2; ++s) {
                const ushort* ap = z + (size_t)(rowW + s * 16 + c) * Dd;
#pragma unroll
                for (int kt = 0; kt < 4; ++kt)
                    afrag[s][kt] = *(const bf16x8*)(ap + kt * 32 + q * 8);
            }
        }

        // deferred col-credit flush from previous half-tile
        if (pendP) { colflush(rowsum, csumP, C0P, lane, c); pendP = false; }

        // next half-tile coords + prefetch-stage into the other buffer
        int trN = tr, ctN = ct + 1;
        if (ctN == 256) { trN = tr + 1; ctN = 2 * trN; }
        if (j + 1 < K_TILES) stage_tile(z, &ldsb[cur ^ 1][0], ctN << 6, wave, lane);

        const char* lb = (const char*)&ldsb[cur][0];
        float csum[4];
#pragma unroll
        for (int st = 0; st < 4; ++st) csum[st] = 0.f;

        // ---- acc-pipelined phase loop: 5 phases over 4 st's (R8 schedule).
        f32x4 acc[2][2];
#pragma unroll
        for (int st = 0; st < 5; ++st) {
            const int p = st & 1;
            if (st < 4) {
                bf16x8 bcur[4];
#pragma unroll
                for (int kt = 0; kt < 4; ++kt)
                    bcur[kt] = *(const bf16x8*)(lb + O[kt] + st * 4096);
#pragma unroll
                for (int s = 0; s < 2; ++s)
                    acc[p][s] = __builtin_amdgcn_mfma_f32_16x16x32_bf16(afrag[s][0], bcur[0], Z4, 0, 0, 0);
#pragma unroll
                for (int kt = 1; kt < 4; ++kt) {
#pragma unroll
                    for (int s = 0; s < 2; ++s)
                        acc[p][s] = __builtin_amdgcn_mfma_f32_16x16x32_bf16(afrag[s][kt], bcur[kt], acc[p][s], 0, 0, 0);
                }
            }
            if (st > 0) {
                const int stP = st - 1;         // phase being finished
                const int pp = p ^ 1;
                const int gc0 = C0 + stP * 16;
#pragma unroll
                for (int s = 0; s < 2; ++s) {
                    const int R = rowW + s * 16;
                    float sp[4];
#pragma unroll
                    for (int r = 0; r < 4; ++r) {
                        float u = acc[pp][s][r];
                        // softplus in log2 domain: max(u,0) + log2(1 + 2^-|u|)
                        float e = __builtin_amdgcn_exp2f(-fabsf(u));
                        // log2(1+e) via degree-5 minimax poly (|err|<=1.5e-4)
                        float pl = e * (1.4419673f + e * (-0.7096745f + e * (0.4176249f
                                  + e * (-0.1963006f + e * 0.0463949f))));
                        sp[r] = fmaxf(u, 0.f) + pl;
                    }
                    if (diag && gc0 == R) {               // zero self-similarity
#pragma unroll
                        for (int r = 0; r < 4; ++r)
                            if (c == q * 4 + r) sp[r] = 0.f;
                    }
                    if (gc0 == (R ^ Bh)) {                // positive-pair subtile
                        // (wave-uniform; rare; R<Bh guaranteed: R>=Bh would
                        // be below-diagonal and never enumerated here)
#pragma unroll
                        for (int r = 0; r < 4; ++r)
                            if (c == q * 4 + r)
                                pacc += __logf(fmaxf(LN2 * sp[r], EPS));
                    }
#pragma unroll
                    for (int r = 0; r < 4; ++r) rs[s][r] += sp[r];
                    if (!diag) csum[stP] += (sp[0] + sp[1]) + (sp[2] + sp[3]);
                }
            }
        }

        if (!diag) {    // defer the col-credit atomics past the barrier
#pragma unroll
            for (int st = 0; st < 4; ++st) csumP[st] = csum[st];
            C0P = C0;
            pendP = true;
        }

        __syncthreads();        // drains vmcnt(0): stage + atomics all a phase old
        cur ^= 1;
        tr = trN;
        ct = ctN;
    }

    if (pendP) colflush(rowsum, csumP, C0P, lane, c);
    if (cur_tr >= 0) flush_rs(rowsum, rowW, rs, q, c);

    // positive-pair contribution: wave-reduce pacc, one atomic per wave (x2:
    // each pair element appears twice in the full N-sum)
    {
        float v = pacc;
#pragma unroll
        for (int m = 1; m < 64; m <<= 1) v += __shfl_xor(v, m);
        if (lane == 0 && v != 0.f) atomicAdd(possum, v + v);
    }

    // ---- last-block finalize (no fences; ILP-batched loads) ----
    __syncthreads();                       // barrier drain: all my atomics done
    int* shi = (int*)&ldsb[0][0];          // LDS dead now: reuse
    if (tid == 0) shi[0] = atomicAdd(counter, 1);
    __syncthreads();
    if (shi[0] == N_BLOCKS - 1) {
        float acc = 0.f;                   // sum of log(denom_i)
        // 16384 / 256 threads = 64 elems/thread; 8 batches of 8 independent
        // loads -> ~8 coherent-point round-trips instead of 64.
#pragma unroll
        for (int b = 0; b < 8; ++b) {
            float v[8];
#pragma unroll
            for (int k = 0; k < 8; ++k)
                v[k] = __hip_atomic_load(&rowsum[tid + (b * 8 + k) * 256],
                                         __ATOMIC_RELAXED, __HIP_MEMORY_SCOPE_AGENT);
#pragma unroll
            for (int k = 0; k < 8; ++k)
                acc += __logf(fmaxf(LN2 * v[k], EPS));
        }
#pragma unroll
        for (int m = 1; m < 64; m <<= 1) acc += __shfl_xor(acc, m);
        __syncthreads();                   // all have read shi[0]
        float* red = (float*)&ldsb[0][0];
        if (lane == 0) red[wave] = acc;
        __syncthreads();
        if (tid == 0) {
            float ps = __hip_atomic_load(possum, __ATOMIC_RELAXED, __HIP_MEMORY_SCOPE_AGENT);
            float sumden = red[0] + red[1] + red[2] + red[3];
            out[0] = (sumden - ps) / (float)Nn;   // = -(possum - sum(log denom))/N
        }
    }
}

extern "C" void kernel_launch(void* const* d_in, const int* in_sizes, int n_in,
                              void* d_out, int out_size, void* d_ws, size_t ws_size,
                              hipStream_t stream) {
    const float* za = (const float*)d_in[0];
    const float* zb = (const float*)d_in[1];

    // workspace layout: z bf16 (4 MB) | rowsum (16384 f) | counter | possum
    ushort* z = (ushort*)d_ws;
    float* rowsum = (float*)((char*)d_ws + (size_t)Nn * Dd * 2);
    int* counter = (int*)(rowsum + Nn);
    float* possum = (float*)(rowsum + Nn + 32);
    float* out = (float*)d_out;

    convert_kernel<<<2048, 256, 0, stream>>>((const float4*)za, (const float4*)zb, z, rowsum, counter, possum);
    main_kernel<<<N_BLOCKS, 256, 0, stream>>>(z, rowsum, counter, possum, out);
}